// Round 5
// baseline (808.484 us; speedup 1.0000x reference)
//
#include <hip/hip_runtime.h>
#include <hip/hip_cooperative_groups.h>

namespace cg = cooperative_groups;

#define EPS 1e-9f

constexpr int B_ = 8, N_ = 2048, M_ = 2048;
constexpr int THREADS = 512;               // 8 waves/block
constexpr int WAVES = 8;
constexpr int RPW = 8;                     // rows per wave
constexpr int RPB = WAVES * RPW;           // 64 rows per block
constexpr int BPB = N_ / RPB;              // 32 blocks per batch
constexpr int GRID = B_ * BPB;             // 256 blocks = 1/CU (LDS forces 1/CU)
constexpr int CPT = M_ / THREADS;          // 4 staged columns per thread

__global__ __launch_bounds__(256) void init_kernel(float* ss0, float* out) {
    int i = blockIdx.x * blockDim.x + threadIdx.x;
    if (i < B_ * M_) ss0[i] = 0.f;
    if (i < B_) out[i] = 0.f;
}

// Persistent cooperative kernel: all 11 annealing steps in one dispatch.
// Rows are block-private for the whole schedule -> rl/f live in REGISTERS
// (rL/fb global arrays deleted). xyz1 rows and xyz2 columns loaded ONCE into
// registers. Per step: stage (recompute g/rn per column from global rR/ss) ->
// fused sweep (phase2(s-1) + rowsum(s)) -> colsum via ssl -> grid.sync().
// Column state (rR double-buffer, ss triple-buffer) stays global, same
// rotation as the multi-kernel version. e^4 trick reverted (measured slower).
__global__ __launch_bounds__(THREADS, 2) void persist(
        const float* __restrict__ xyz1, const float* __restrict__ xyz2,
        float* __restrict__ rR0, float* __restrict__ rR1,
        float* __restrict__ ss0, float* __restrict__ ss1, float* __restrict__ ss2,
        float* __restrict__ out)
{
    // raw[0:8192)        : sp  = float4 (x,y,z,rn)     32 KB
    // raw[8192:10240)    : sg  = g                      8 KB
    // raw[10240:26624)   : ssl (8 waves x 2048)        64 KB (no overlay needed)
    // raw[26624:26632)   : wcost
    __shared__ __align__(16) float raw[13 * M_ + WAVES];
    float4* sp    = (float4*)raw;
    float*  sg    = raw + 4 * M_;
    float*  ssl   = raw + 5 * M_;
    float*  wcost = raw + 13 * M_;

    float* rRb[2] = { rR0, rR1 };
    float* ssb[3] = { ss0, ss1, ss2 };

    const int b   = blockIdx.x / BPB;
    const int blk = blockIdx.x % BPB;
    const int n0  = blk * RPB;
    const int tid = threadIdx.x;
    const bool designated = (blk == 0);
    const int wave = tid >> 6, lane = tid & 63;
    const int nw = n0 + wave * RPW;

    // ---- one-time loads into persistent registers ----
    float cx[CPT], cy[CPT], cz[CPT];
    #pragma unroll
    for (int i = 0; i < CPT; ++i) {
        const float* q = xyz2 + ((size_t)b * M_ + tid + i * THREADS) * 3;
        cx[i] = q[0]; cy[i] = q[1]; cz[i] = q[2];
    }
    float xv[RPW], yv[RPW], zv[RPW], rl[RPW], fo[RPW];
    #pragma unroll
    for (int r = 0; r < RPW; ++r) {
        const float* q = xyz1 + (size_t)(b * N_ + nw + r) * 3;
        xv[r] = q[0]; yv[r] = q[1]; zv[r] = q[2];
        rl[r] = 1.f; fo[r] = 0.f;
    }

    cg::grid_group grid = cg::this_grid();

    constexpr float LOG2E = 1.4426950408889634f;
    const float levels[10] = { -16384.f, -4096.f, -1024.f, -256.f, -64.f,
                               -16.f, -4.f, -1.f, -0.25f, 0.f };

    for (int s = 0; s <= 10; ++s) {
        const bool has_p2 = (s > 0);
        const bool has_p1 = (s < 10);
        const float l2p = has_p2 ? levels[s - 1] * LOG2E : 0.f;
        const float l2c = has_p1 ? levels[s] * LOG2E : 0.f;
        const float* __restrict__ rRp   = rRb[(s + 1) & 1];
        float*       __restrict__ rRn   = rRb[s & 1];
        const float* __restrict__ ssp_g = ssb[(s + 2) % 3];
        float*       __restrict__ ssc_g = ssb[s % 3];
        float*       __restrict__ ssz_g = ssb[(s + 1) % 3];

        // ---- staging: per-column g/rn (xyz from registers) ----
        #pragma unroll
        for (int i = 0; i < CPT; ++i) {
            const int m = tid + i * THREADS;
            float g = 0.f, rn = 1.f;
            if (has_p2) {
                const float rr = rRp[b * M_ + m];
                const float sv = ssp_g[b * M_ + m];
                const float ratio = fminf(rr / (sv + EPS), 1.f);
                g  = rr * ratio;
                rn = fmaxf(rr - sv * ratio, 0.f);
            }
            sp[m] = make_float4(cx[i], cy[i], cz[i], rn);
            sg[m] = g;
            if (designated) {
                if (has_p1) rRn[b * M_ + m] = rn;
                ssz_g[b * M_ + m] = 0.f;   // zero ss(s+1) for next step
            }
        }
        __syncthreads();

        float accd[RPW], accc[RPW], p[RPW];
        #pragma unroll
        for (int r = 0; r < RPW; ++r) { accd[r] = 0.f; accc[r] = 0.f; p[r] = 0.f; }

        // ---- fused sweep: phase2(s-1) + rowsum(s) ----
        if (has_p2 && has_p1) {
            #pragma unroll
            for (int k = 0; k < 32; ++k) {
                const float4 c = sp[lane + (k << 6)];
                const float  g = sg[lane + (k << 6)];
                #pragma unroll
                for (int r = 0; r < RPW; ++r) {
                    const float dx = xv[r]-c.x, dy = yv[r]-c.y, dz = zv[r]-c.z;
                    const float d2 = dx*dx + dy*dy + dz*dz;
                    const float e = __builtin_amdgcn_exp2f(l2p * d2) * g;
                    accd[r] += e;
                    accc[r] += e * __builtin_amdgcn_sqrtf(fmaxf(d2, 1e-20f));
                    p[r] += __builtin_amdgcn_exp2f(l2c * d2) * c.w;
                }
            }
        } else if (has_p1) {
            // s=0: p-only
            #pragma unroll
            for (int k = 0; k < 32; ++k) {
                const float4 c = sp[lane + (k << 6)];
                #pragma unroll
                for (int r = 0; r < RPW; ++r) {
                    const float dx = xv[r]-c.x, dy = yv[r]-c.y, dz = zv[r]-c.z;
                    const float d2 = dx*dx + dy*dy + dz*dz;
                    p[r] += __builtin_amdgcn_exp2f(l2c * d2) * c.w;
                }
            }
        } else {
            // s=10: phase2-only
            #pragma unroll
            for (int k = 0; k < 32; ++k) {
                const float4 c = sp[lane + (k << 6)];
                const float  g = sg[lane + (k << 6)];
                #pragma unroll
                for (int r = 0; r < RPW; ++r) {
                    const float dx = xv[r]-c.x, dy = yv[r]-c.y, dz = zv[r]-c.z;
                    const float d2 = dx*dx + dy*dy + dz*dz;
                    const float e = __builtin_amdgcn_exp2f(l2p * d2) * g;
                    accd[r] += e;
                    accc[r] += e * __builtin_amdgcn_sqrtf(fmaxf(d2, 1e-20f));
                }
            }
        }

        // ---- wave reductions (rows are wave-private) ----
        if (has_p2) {
            #pragma unroll
            for (int r = 0; r < RPW; ++r) {
                #pragma unroll
                for (int off = 32; off >= 1; off >>= 1) {
                    accd[r] += __shfl_xor(accd[r], off, 64);
                    accc[r] += __shfl_xor(accc[r], off, 64);
                }
            }
        }
        if (has_p1) {
            #pragma unroll
            for (int r = 0; r < RPW; ++r) {
                #pragma unroll
                for (int off = 32; off >= 1; off >>= 1)
                    p[r] += __shfl_xor(p[r], off, 64);
            }
        }

        // ---- row state update (registers only) ----
        float cw = 0.f;
        float rl_new[RPW];
        if (has_p2) {
            #pragma unroll
            for (int r = 0; r < RPW; ++r) {
                rl_new[r] = fmaxf(rl[r] - fo[r] * accd[r], 0.f);
                cw += fo[r] * accc[r];
            }
        } else {
            #pragma unroll
            for (int r = 0; r < RPW; ++r) rl_new[r] = rl[r];
        }
        if (lane == 0) wcost[wave] = cw;

        if (has_p1) {
            float fn[RPW];
            #pragma unroll
            for (int r = 0; r < RPW; ++r) {
                fn[r] = rl_new[r] / (p[r] + EPS);
                rl[r] = rl_new[r];
                fo[r] = fn[r];
            }
            // ---- colsum: per-lane column partials -> ssl -> global atomics ----
            float ssp[32];
            #pragma unroll
            for (int k = 0; k < 32; ++k) {
                const float4 c = sp[lane + (k << 6)];
                float sacc = 0.f;
                #pragma unroll
                for (int r = 0; r < RPW; ++r) {
                    const float dx = xv[r]-c.x, dy = yv[r]-c.y, dz = zv[r]-c.z;
                    const float d2 = dx*dx + dy*dy + dz*dz;
                    sacc += __builtin_amdgcn_exp2f(l2c * d2) * fn[r];
                }
                ssp[k] = sacc * c.w;
            }
            #pragma unroll
            for (int k = 0; k < 32; ++k)
                ssl[wave * M_ + lane + (k << 6)] = ssp[k];
            __syncthreads();   // ssl complete; wcost visible
            if (tid == 0 && has_p2) {
                float t = 0.f;
                #pragma unroll
                for (int w = 0; w < WAVES; ++w) t += wcost[w];
                atomicAdd(&out[b], t);
            }
            for (int m = tid; m < M_; m += THREADS) {
                float sacc = ssl[m]        + ssl[M_ + m]   + ssl[2*M_ + m]
                           + ssl[3*M_ + m] + ssl[4*M_ + m] + ssl[5*M_ + m]
                           + ssl[6*M_ + m] + ssl[7*M_ + m];
                atomicAdd(&ssc_g[b * M_ + m], sacc);
            }
        } else {
            __syncthreads();   // wcost visible
            if (tid == 0) {
                float t = 0.f;
                #pragma unroll
                for (int w = 0; w < WAVES; ++w) t += wcost[w];
                atomicAdd(&out[b], t);
            }
        }

        grid.sync();   // ss(s)/rR(s)/zeroed ss(s+1) globally visible
    }
}

extern "C" void kernel_launch(void* const* d_in, const int* in_sizes, int n_in,
                              void* d_out, int out_size, void* d_ws, size_t ws_size,
                              hipStream_t stream) {
    const float* xyz1 = (const float*)d_in[0];
    const float* xyz2 = (const float*)d_in[1];
    float* out = (float*)d_out;
    float* ws = (float*)d_ws;
    const int SZ = B_ * M_;          // 16384
    float* rR0 = ws;
    float* rR1 = ws + SZ;
    float* ss0 = ws + 2 * SZ;
    float* ss1 = ws + 3 * SZ;
    float* ss2 = ws + 4 * SZ;

    init_kernel<<<(SZ + 255) / 256, 256, 0, stream>>>(ss0, out);

    void* args[] = { (void*)&xyz1, (void*)&xyz2,
                     (void*)&rR0, (void*)&rR1,
                     (void*)&ss0, (void*)&ss1, (void*)&ss2,
                     (void*)&out };
    hipLaunchCooperativeKernel((const void*)persist, dim3(GRID), dim3(THREADS),
                               args, 0, stream);
}